// Round 3
// baseline (292.582 us; speedup 1.0000x reference)
//
#include <hip/hip_runtime.h>
#include <stdint.h>

// VQ-VAE quantizer: z [16,4096,64] f32, embedding [1024,64] f32.
// d_out (f32): [0]=loss, [1..4194304]=z_q, [4194305..]=indices (as float).
//
// Bitwise-argmin machinery (verified absmax 0.0 in R1/R2 — do not touch):
//   d = fmaf(-2, dot, (zz+ee)); zz/ee = numpy pairwise 8-acc tree, contract
//   OFF; dot = (p0+p1)+(p2+p3) fmaf chains; strict < => first-index ties;
//   segments merged in ascending j order.
//
// R3: R2 was LDS-bound — VGPR_Count=40 proved the compiler rematerialized
// zr[64] from LDS per code (16KB LDS traffic/code). Fixes:
//  * z-tile LDS region is REUSED as the codebook DMA buffer -> remat illegal,
//    zr stays in VGPRs (launch_bounds(256,4) gives 128-VGPR headroom).
//  * e-rows streamed via global_load_lds (16B/lane, 1KB=4 codes per instr)
//    into per-wave double buffers; hot loop reads are wave-uniform
//    ds_read_b128 broadcasts (16B bank traffic each).
//  * explicit s_waitcnt vmcnt(1/0) + sched_barrier pipelining, no barriers
//    in the scan loop.

#define D 64
#define NE 1024
#define SEGS 4           // waves per block, each scans NE/SEGS codes
#define CPS 256          // codes per segment
#define ROWS 64          // rows per block (one per lane)
#define TPB 256
#define ZSTRIDE 68       // 64 + 4 pad; (17*lane+c)%32 -> worst 2-way (free)

// s_waitcnt simm16 (gfx9 encoding): [3:0]=vmcnt lo, [6:4]=expcnt,
// [11:8]=lgkmcnt, [15:14]=vmcnt hi.
#define WAIT_VMCNT1 0x0F71   // vmcnt(1), expcnt/lgkmcnt don't-care
#define WAIT_VMCNT0 0x0F70   // vmcnt(0)
#define WAIT_LGKM0  0xC07F   // lgkmcnt(0), vmcnt don't-care

typedef const __attribute__((address_space(1))) void* gas_t;
typedef __attribute__((address_space(3))) void* las_t;

__device__ __forceinline__ void dma_4rows(const float* gsrc, float* ldst, int lane) {
    // 64 lanes x 16B = 1024B = 4 codebook rows -> LDS (wave-uniform base).
    __builtin_amdgcn_global_load_lds((gas_t)(gsrc + lane * 4), (las_t)ldst, 16, 0, 0);
}

__global__ __launch_bounds__(TPB, 4) void vq_kernel(const float* __restrict__ z,
                                                    const float* __restrict__ emb,
                                                    float* __restrict__ out_loss,
                                                    float* __restrict__ out_zq,
                                                    float* __restrict__ out_idx,
                                                    float loss_scale) {
    // pool0: z tile (64x68) -> reused as codebook DMA buffer (4 segs x 512 f)
    //        -> finally holds z_q for the coalesced store.
    // pool1: ee[1024] -> reused as merge arrays (smv [0:256), smi [256:512)).
    __shared__ __align__(16) float pool0[ROWS * ZSTRIDE];
    __shared__ __align__(16) float pool1[NE];

    const int tid  = threadIdx.x;
    const int lane = tid & 63;
    const size_t blockRow = (size_t)blockIdx.x * ROWS;

    // --- Stage z tile (64 rows x 64) coalesced into LDS. ---
    const float4* zg4 = (const float4*)(z + blockRow * D);
#pragma unroll
    for (int it = 0; it < 4; ++it) {
        int i = it * TPB + tid;            // 0..1023 float4s
        int row = i >> 4, col = i & 15;
        float4 v = zg4[i];
        *(float4*)&pool0[row * ZSTRIDE + col * 4] = v;
    }

    // --- ee[j]: numpy-pairwise sum(e*e), contract off (bitwise np mirror). ---
    {
#pragma clang fp contract(off)
#pragma unroll
        for (int cc = 0; cc < 4; ++cc) {
            const int j = tid + cc * TPB;
            const float4* e4 = (const float4*)(emb + ((size_t)j << 6));
            float4 a = e4[0], b = e4[1];
            float r[8];
            r[0] = a.x*a.x; r[1] = a.y*a.y; r[2] = a.z*a.z; r[3] = a.w*a.w;
            r[4] = b.x*b.x; r[5] = b.y*b.y; r[6] = b.z*b.z; r[7] = b.w*b.w;
#pragma unroll
            for (int g = 1; g < 8; ++g) {
                float4 c = e4[2*g], e = e4[2*g + 1];
                r[0] = r[0] + c.x*c.x; r[1] = r[1] + c.y*c.y;
                r[2] = r[2] + c.z*c.z; r[3] = r[3] + c.w*c.w;
                r[4] = r[4] + e.x*e.x; r[5] = r[5] + e.y*e.y;
                r[6] = r[6] + e.z*e.z; r[7] = r[7] + e.w*e.w;
            }
            pool1[j] = ((r[0]+r[1]) + (r[2]+r[3])) + ((r[4]+r[5]) + (r[6]+r[7]));
        }
    }
    __syncthreads();

    // --- z row (row = lane) into VGPRs; zz = np-pairwise sum(z*z). ---
    float zr[D];
#pragma unroll
    for (int c = 0; c < 16; ++c) {
        float4 v = *(const float4*)&pool0[lane * ZSTRIDE + c * 4];
        zr[4*c+0] = v.x; zr[4*c+1] = v.y; zr[4*c+2] = v.z; zr[4*c+3] = v.w;
    }
    float zz;
    {
#pragma clang fp contract(off)
        float r[8];
#pragma unroll
        for (int jj = 0; jj < 8; ++jj) { float t = zr[jj] * zr[jj]; r[jj] = t; }
#pragma unroll
        for (int i = 8; i < 64; i += 8) {
#pragma unroll
            for (int jj = 0; jj < 8; ++jj) { float t = zr[i+jj] * zr[i+jj]; r[jj] = r[jj] + t; }
        }
        zz = ((r[0]+r[1]) + (r[2]+r[3])) + ((r[4]+r[5]) + (r[6]+r[7]));
    }
    __syncthreads();   // all zr reads drained (lgkmcnt(0) at barrier) before DMA clobbers pool0

    // --- Scan this wave's 256-code segment; DMA double-buffer, 4 codes/chunk. ---
    const int seg   = __builtin_amdgcn_readfirstlane(tid >> 6);
    float* cbuf     = &pool0[seg * 512];             // 2 x 256 floats
    const int jbase = seg * CPS;
    const float* gseg = emb + ((size_t)jbase << 6);

    float minv = __builtin_inff();
    int   mini = 0;

    dma_4rows(gseg + 0 * 256, cbuf + 0,   lane);     // chunk 0 -> half 0
    dma_4rows(gseg + 1 * 256, cbuf + 256, lane);     // chunk 1 -> half 1

    for (int ch = 0; ch < 64; ++ch) {
        if (ch == 63) __builtin_amdgcn_s_waitcnt(WAIT_VMCNT0);
        else          __builtin_amdgcn_s_waitcnt(WAIT_VMCNT1);
        __builtin_amdgcn_sched_barrier(0);           // don't hoist ds_reads above the wait
        const float* cb = &cbuf[(ch & 1) * 256];
#pragma unroll
        for (int cc = 0; cc < 4; ++cc) {
            const int j = jbase + ch * 4 + cc;
            float p0 = 0.f, p1 = 0.f, p2 = 0.f, p3 = 0.f;
#pragma unroll
            for (int c = 0; c < 16; ++c) {
                float4 e4 = *(const float4*)&cb[cc * 64 + c * 4];  // uniform addr -> broadcast
                p0 = fmaf(zr[4*c+0], e4.x, p0);
                p1 = fmaf(zr[4*c+1], e4.y, p1);
                p2 = fmaf(zr[4*c+2], e4.z, p2);
                p3 = fmaf(zr[4*c+3], e4.w, p3);
            }
            float dot = (p0 + p1) + (p2 + p3);
            float t1 = zz + pool1[j];              // mirrors np (zz + ee) rounding
            float d = fmaf(-2.0f, dot, t1);        // == round(t1 - 2*dot)
            if (d < minv) { minv = d; mini = j; }  // strict < -> first index on tie
        }
        if (ch < 62) {
            __builtin_amdgcn_s_waitcnt(WAIT_LGKM0);   // ds_reads of this half drained (WAR)
            __builtin_amdgcn_sched_barrier(0);
            dma_4rows(gseg + (ch + 2) * 256, cbuf + (ch & 1) * 256, lane);
        }
    }

    __syncthreads();   // scans done everywhere; ee (pool1) now dead
    pool1[seg * 64 + lane]       = minv;           // smv
    pool1[256 + seg * 64 + lane] = (float)mini;    // smi (exact for <=1024)
    __syncthreads();

    if (tid < ROWS) {                              // wave 0: merge + epilogue
        float best = __builtin_inff();
        int bi = 0;
#pragma unroll
        for (int s = 0; s < SEGS; ++s) {           // ascending seg = ascending j
            float v = pool1[s * 64 + tid];
            if (v < best) { best = v; bi = (int)pool1[256 + s * 64 + tid]; }
        }

        // Gather winning code row; z_q = z + (q - z); loss partial.
        const float4* qe4 = (const float4*)(emb + ((size_t)bi << 6));
        float s = 0.f;
#pragma unroll
        for (int c = 0; c < 16; ++c) {
            float4 q = qe4[c];
            float z0 = zr[4*c+0], z1 = zr[4*c+1], z2 = zr[4*c+2], z3 = zr[4*c+3];
            float d0 = q.x - z0, d1 = q.y - z1, d2 = q.z - z2, d3 = q.w - z3;
            s += d0*d0; s += d1*d1; s += d2*d2; s += d3*d3;
            float4 o;
            o.x = z0 + d0; o.y = z1 + d1; o.z = z2 + d2; o.w = z3 + d3;
            *(float4*)&pool0[tid * ZSTRIDE + c * 4] = o;   // codebuf dead -> z_q tile
        }
        out_idx[blockRow + tid] = (float)bi;

        // loss = 1.25 * mean((q-z)^2): wave reduce + one atomic per block.
#pragma unroll
        for (int off = 32; off; off >>= 1) s += __shfl_down(s, off);
        if (tid == 0) atomicAdd(out_loss, s * loss_scale);
    }
    __syncthreads();

    // Coalesced z_q store (out_zq = d_out+1 is 4B-aligned -> dword stores).
    const size_t obase = blockRow * D;
#pragma unroll
    for (int it = 0; it < 16; ++it) {
        int i = it * TPB + tid;            // 0..4095 floats
        int row = i >> 6, col = i & 63;
        out_zq[obase + i] = pool0[row * ZSTRIDE + col];
    }
}

extern "C" void kernel_launch(void* const* d_in, const int* in_sizes, int n_in,
                              void* d_out, int out_size, void* d_ws, size_t ws_size,
                              hipStream_t stream) {
    const float* z   = (const float*)d_in[0];
    const float* emb = (const float*)d_in[1];
    const int nz = in_sizes[0];          // 4194304
    const int N  = nz / D;               // 65536 rows

    float* out      = (float*)d_out;
    float* out_zq   = out + 1;
    float* out_idx  = out + 1 + (size_t)nz;

    const float loss_scale = 1.25f / (float)nz;

    hipMemsetAsync(out, 0, sizeof(float), stream);  // loss accumulator
    vq_kernel<<<N / ROWS, TPB, 0, stream>>>(z, emb, out, out_zq, out_idx, loss_scale);
}